// Round 18
// baseline (58378.558 us; speedup 1.0000x reference)
//
#include <hip/hip_runtime.h>

#define HID 512
#define NB  64
#define NT  1024
#define THX 0.1f
#define THH 0.05f
#define NG  16     // batch groups
#define GB  4      // batches per group

// ---- prep: pack W_ih_l0 [1536][6] f32 -> [6][512]{r,z,n} float3 ----
__global__ void pack_ih0(const float* __restrict__ src, float* __restrict__ dst) {
    int idx = blockIdx.x * blockDim.x + threadIdx.x;
    if (idx < 6 * HID) {
        int f = idx / HID, j = idx % HID;
        dst[f * 1536 + j * 3 + 0] = src[(0 * HID + j) * 6 + f];
        dst[f * 1536 + j * 3 + 1] = src[(1 * HID + j) * 6 + f];
        dst[f * 1536 + j * 3 + 2] = src[(2 * HID + j) * 6 + f];
    }
}

// ---- prep: pack a [1536][512] f32 matrix -> [512(k)][512(j)]{r,z,n|nh} ----
__global__ void pack_h3(const float* __restrict__ src, float* __restrict__ dst) {
    int idx = blockIdx.x * blockDim.x + threadIdx.x;
    if (idx < HID * HID) {
        int k = idx / HID, j = idx % HID;
        dst[k * 1536 + j * 3 + 0] = src[(0 * HID + j) * HID + k];
        dst[k * 1536 + j * 3 + 1] = src[(1 * HID + j) * HID + k];
        dst[k * 1536 + j * 3 + 2] = src[(2 * HID + j) * HID + k];
    }
}

// ---- init: zero panels + tags (slot3 tag 0 == expected at t=0) ----
__global__ void init_ws(float* __restrict__ panels, int* __restrict__ tags) {
    int i = blockIdx.x * blockDim.x + threadIdx.x;
    if (i < 4 * NG * 4 * 3 * 512) panels[i] = 0.f;
    if (i < 4 * NG * 4) tags[i] = 0;
}

__device__ __forceinline__ int poff(int slot, int g, int q, int kind) {
    return (((slot * NG + g) * 4 + q) * 3 + kind) * 512;   // floats
}
__device__ __forceinline__ int tdx(int slot, int g, int q) {
    return (slot * NG + g) * 4 + q;
}

// ---- coherent RELAXED ops only (r17: no release -> no L2 flush storms) ----
__device__ __forceinline__ int ld_tag(const int* p) {
    return __hip_atomic_load(p, __ATOMIC_RELAXED, __HIP_MEMORY_SCOPE_AGENT);
}
__device__ __forceinline__ float ld_f(const float* p) {
    return __uint_as_float(__hip_atomic_load((const unsigned*)p,
                           __ATOMIC_RELAXED, __HIP_MEMORY_SCOPE_AGENT));
}
__device__ __forceinline__ void st_f(float* p, float v) {
    __hip_atomic_store((unsigned*)p, __float_as_uint(v),
                       __ATOMIC_RELAXED, __HIP_MEMORY_SCOPE_AGENT);
}
__device__ __forceinline__ void st_tag(int* p, int v) {
    __hip_atomic_store(p, v, __ATOMIC_RELAXED, __HIP_MEMORY_SCOPE_AGENT);
}

// ---- dense batched MAC: thread (u, s) walks rows k = s, s+8, ..., s+504 ----
// Per row: 1 float3 weight load (12B, L2-resident) + 1 ds_read_b128 (4 batches'
// deltas) + 12 fma -> each weight byte serves 4 batches (vs 1 in r10-r17:
// the L2-BW fix). depth-4 named-scalar pipeline (the only shape hipcc holds).
// Writes 12 slot-partials to pp[j*128] (= s_pp[s][j][u]), j = gate*4+batch.
__device__ __forceinline__ void mac_dense(const float* __restrict__ wq,
                                          const float4* __restrict__ pv0,
                                          int colbyte, int s,
                                          float* __restrict__ pp) {
    const char* base = (const char*)wq + colbyte + s * 6144;
    const float4* pv = pv0 + s;
    float a0=0,a1=0,a2=0,a3=0,a4=0,a5=0,a6=0,a7=0,a8=0,a9=0,a10=0,a11=0;
    float4 d0, d1, d2, d3;
    float3 w0, w1, w2, w3;
#define LDD(S, J) { w##S = *(const float3*)(base + (size_t)(J) * 49152); \
                    d##S = pv[(J) * 8]; }
#define COD(S, JN, MORE) { float3 W_ = w##S; float4 D_ = d##S; \
    if (MORE) LDD(S, (JN)) \
    a0 += D_.x * W_.x;  a1 += D_.y * W_.x;  a2  += D_.z * W_.x;  a3  += D_.w * W_.x; \
    a4 += D_.x * W_.y;  a5 += D_.y * W_.y;  a6  += D_.z * W_.y;  a7  += D_.w * W_.y; \
    a8 += D_.x * W_.z;  a9 += D_.y * W_.z;  a10 += D_.z * W_.z;  a11 += D_.w * W_.z; }
    LDD(0,0) LDD(1,1) LDD(2,2) LDD(3,3)
    #pragma unroll 1
    for (int j = 0; j < 64; j += 4) {
        const bool m = (j + 4) < 64;
        COD(0, j+4, m) COD(1, j+5, m) COD(2, j+6, m) COD(3, j+7, m)
    }
#undef LDD
#undef COD
    pp[0]      = a0;  pp[128]    = a1;  pp[2*128]  = a2;  pp[3*128]  = a3;
    pp[4*128]  = a4;  pp[5*128]  = a5;  pp[6*128]  = a6;  pp[7*128]  = a7;
    pp[8*128]  = a8;  pp[9*128]  = a9;  pp[10*128] = a10; pp[11*128] = a11;
}

// ---- main kernel: 64 WGs = 16 batch-groups x 4 unit-quarters, both layers --
// Dense delta panels (128u x 4b x 3 kinds, 6KB/WG/step) exchanged via r17's
// tag protocol (4-deep rotation, relaxed stores, vmcnt-drain-then-tag).
// wgid%8 in {q, q+4}: each XCD caches one quarter weight slice (2.25MB).
__global__ __launch_bounds__(1024, 2)
void dgru_d(const float* __restrict__ x,
            const float* __restrict__ wih0p,   // [6][512] float3
            const float* __restrict__ whh0p,   // [512][512] float3 (r,z,nh)
            const float* __restrict__ wih1p,   // (r,z,n)
            const float* __restrict__ whh1p,   // (r,z,nh)
            const float* __restrict__ bih0, const float* __restrict__ bhh0,
            const float* __restrict__ bih1, const float* __restrict__ bhh1,
            const float* __restrict__ wfc,
            float* __restrict__ panels, int* __restrict__ tags,
            float* __restrict__ ws_fc) {
    __shared__ float  s_x4[GB][2 * NT];            // 32 KB
    __shared__ float4 s_pA[512];                   // [k][4b] dh0   8 KB
    __shared__ float4 s_pB[512];                   // dx1           8 KB
    __shared__ float4 s_pC[512];                   // dh1           8 KB
    __shared__ float  s_pp[8][12][128];            // 48 KB slot partials
    __shared__ float  s_dx0[GB][8];
    __shared__ float  s_xp0[GB][8];
    __shared__ float  s_fcp[8][2];

    const int wgid = blockIdx.x;
    const int g    = wgid >> 2;
    const int q    = wgid & 3;
    const int tid  = threadIdx.x;
    const int u    = tid & 127;
    const int s    = tid >> 7;        // MAC slot 0..7 (k-row mod 8)
    const int b    = tid >> 7;        // batch-in-group for unit threads (tid<512)
    const int uu   = q * 128 + u;
    const int lane = tid & 63;
    const int wave = tid >> 6;
    const int colbyte = uu * 12;

    // unit-thread state (tid<512): per (b, uu)
    float h0=0.f, h0p=0.f, xp1=0.f, h1=0.f, h1p=0.f;
    float cr0=0.f, cz0=0.f, cn0=0.f, cnh0=0.f;
    float cr1=0.f, cz1=0.f, cn1=0.f, cnh1=0.f;
    float wf0=0.f, wf1=0.f;
    if (tid < 512) {
        cr0  = bih0[uu]         + bhh0[uu];
        cz0  = bih0[HID + uu]   + bhh0[HID + uu];
        cn0  = bih0[2*HID + uu];
        cnh0 = bhh0[2*HID + uu];
        cr1  = bih1[uu]         + bhh1[uu];
        cz1  = bih1[HID + uu]   + bhh1[HID + uu];
        cn1  = bih1[2*HID + uu];
        cnh1 = bhh1[2*HID + uu];
        wf0 = wfc[uu]; wf1 = wfc[HID + uu];
    }

    for (int i = tid; i < GB * 2 * NT; i += 1024) {
        int bb = i >> 11, idx = i & (2 * NT - 1);
        s_x4[bb][idx] = x[(size_t)(g * GB + bb) * 2 * NT + idx];
    }
    if (tid < GB * 8) { s_xp0[tid >> 3][tid & 7] = 0.f; s_dx0[tid >> 3][tid & 7] = 0.f; }
    __syncthreads();

    for (int t = 0; t <= NT; ++t) {
        const int slot_r = (t + 3) & 3, slot_w = t & 3;
        // ===== poll the 4 quarter tags (full-int compare, no aliasing) =====
        if (tid < 4) {
            const int* tp = tags + tdx(slot_r, g, tid);
            while (ld_tag(tp) != t) __builtin_amdgcn_s_sleep(2);
        }
        __syncthreads();                                   // S0
        // ===== stage panels -> LDS [k][4b], + input features ==============
        if (t < NT) {
            for (int i = tid; i < 2048; i += 1024) {
                int qq = i >> 9, rem = i & 511;
                ((float*)s_pA)[i] = ld_f(panels + poff(slot_r, g, qq, 0) + rem);
            }
            if (tid < 32) {
                int bb = tid >> 3, f = tid & 7;
                if (f < 6) {
                    float iv = s_x4[bb][2 * t], qv = s_x4[bb][2 * t + 1];
                    float amp = sqrtf(iv * iv + qv * qv);
                    float fv;
                    if      (f == 0) fv = iv;
                    else if (f == 1) fv = qv;
                    else if (f == 2) fv = amp;
                    else if (f == 3) fv = amp * amp * amp;
                    else if (f == 4) fv = qv / amp;
                    else             fv = iv / amp;
                    float dx = fv - s_xp0[bb][f];
                    if (fabsf(dx) < THX) dx = 0.f; else s_xp0[bb][f] = fv;
                    s_dx0[bb][f] = dx;
                }
            }
        }
        if (t > 0) {
            for (int i = tid; i < 2048; i += 1024) {
                int qq = i >> 9, rem = i & 511;
                ((float*)s_pB)[i] = ld_f(panels + poff(slot_r, g, qq, 1) + rem);
                ((float*)s_pC)[i] = ld_f(panels + poff(slot_r, g, qq, 2) + rem);
            }
        }
        __syncthreads();                                   // S1

        float l0R=0.f, l0Z=0.f, l0NH=0.f;
        float l1iR=0.f, l1iZ=0.f, l1iN=0.f;
        float l1hR=0.f, l1hZ=0.f, l1hNH=0.f;

        // ===== PHASE 1: whh0 x dh0 ========================================
        if (t < NT) mac_dense(whh0p, s_pA, colbyte, s, &s_pp[s][0][u]);
        __syncthreads();                                   // S2a
        if (t < NT && tid < 512) {
            #pragma unroll
            for (int ss = 0; ss < 8; ++ss) {
                l0R  += s_pp[ss][0*4 + b][u];
                l0Z  += s_pp[ss][1*4 + b][u];
                l0NH += s_pp[ss][2*4 + b][u];
            }
        }
        __syncthreads();                                   // S2b
        // ===== PHASE 2: wih1 x dx1 ========================================
        if (t > 0) mac_dense(wih1p, s_pB, colbyte, s, &s_pp[s][0][u]);
        __syncthreads();                                   // S2c
        if (t > 0 && tid < 512) {
            #pragma unroll
            for (int ss = 0; ss < 8; ++ss) {
                l1iR += s_pp[ss][0*4 + b][u];
                l1iZ += s_pp[ss][1*4 + b][u];
                l1iN += s_pp[ss][2*4 + b][u];
            }
        }
        __syncthreads();                                   // S2d
        // ===== PHASE 3: whh1 x dh1 ========================================
        if (t > 0) mac_dense(whh1p, s_pC, colbyte, s, &s_pp[s][0][u]);
        __syncthreads();                                   // S2e
        if (t > 0 && tid < 512) {
            #pragma unroll
            for (int ss = 0; ss < 8; ++ss) {
                l1hR  += s_pp[ss][0*4 + b][u];
                l1hZ  += s_pp[ss][1*4 + b][u];
                l1hNH += s_pp[ss][2*4 + b][u];
            }
        }

        // ===== unit phase: gates, h updates, deltas, publish, FC ==========
        if (tid < 512) {
            float dA = 0.f, dB = 0.f, dC = 0.f;
            if (t < NT) {
                float iR = 0.f, iZ = 0.f, iN = 0.f;
                #pragma unroll
                for (int f = 0; f < 6; ++f) {              // dv==0 adds exact +0
                    float dv = s_dx0[b][f];
                    const float* wr = wih0p + f * 1536 + uu * 3;
                    iR += dv * wr[0]; iZ += dv * wr[1]; iN += dv * wr[2];
                }
                float ar  = cr0 + iR + l0R;                // carry + mac_x + mac_h
                float az  = cz0 + iZ + l0Z;
                float an  = cn0 + iN;
                float anh = cnh0 + l0NH;
                cr0 = ar; cz0 = az; cn0 = an; cnh0 = anh;
                float r = 1.f / (1.f + expf(-ar));
                float z = 1.f / (1.f + expf(-az));
                float n = tanhf(an + r * anh);
                h0 = (1.f - z) * n + z * h0;
                dA = h0 - h0p; if (fabsf(dA) < THH) dA = 0.f; else h0p = h0;
                dB = h0 - xp1; if (fabsf(dB) < THX) dB = 0.f; else xp1 = h0;
            }
            if (t > 0) {
                float ar  = cr1 + l1iR + l1hR;
                float az  = cz1 + l1iZ + l1hZ;
                float an  = cn1 + l1iN;
                float anh = cnh1 + l1hNH;
                cr1 = ar; cz1 = az; cn1 = an; cnh1 = anh;
                float r = 1.f / (1.f + expf(-ar));
                float z = 1.f / (1.f + expf(-az));
                float n = tanhf(an + r * anh);
                h1 = (1.f - z) * n + z * h1;
                float p0 = h1 * wf0, p1 = h1 * wf1;
                #pragma unroll
                for (int off = 32; off > 0; off >>= 1) {
                    p0 += __shfl_down(p0, off, 64);
                    p1 += __shfl_down(p1, off, 64);
                }
                if (lane == 0) { s_fcp[wave][0] = p0; s_fcp[wave][1] = p1; }
            }
            if (t < NT) {
                dC = h1 - h1p; if (fabsf(dC) < THH) dC = 0.f; else h1p = h1;
                int po = u * 4 + b;
                st_f(panels + poff(slot_w, g, q, 0) + po, dA);
                st_f(panels + poff(slot_w, g, q, 1) + po, dB);
                st_f(panels + poff(slot_w, g, q, 2) + po, dC);
            }
        }
        __syncthreads();     // S4: vmcnt(0) drain -> panel stores complete at LLC
        if (t > 0 && tid < 4) {
            float q0 = s_fcp[2*tid][0] + s_fcp[2*tid + 1][0];
            float q1 = s_fcp[2*tid][1] + s_fcp[2*tid + 1][1];
            float2* dst = (float2*)(ws_fc +
                (((size_t)(g * GB + tid) * NT + (t - 1)) * 4 + q) * 2);
            *dst = make_float2(q0, q1);
        }
        if (t < NT && tid == 0) st_tag(tags + tdx(slot_w, g, q), t + 1);
    }
}

// ---- epilogue: deterministic FC reduction over 4 quarters (ascending) ----
__global__ void fc_reduce(const float* __restrict__ ws_fc,
                          const float* __restrict__ bfc,
                          float* __restrict__ out) {
    int idx = blockIdx.x * blockDim.x + threadIdx.x;   // (b*NT + t)
    if (idx < NB * NT) {
        const float2* p = (const float2*)(ws_fc + (size_t)idx * 8);
        out[idx * 2 + 0] = bfc[0] + p[0].x + p[1].x + p[2].x + p[3].x;
        out[idx * 2 + 1] = bfc[1] + p[0].y + p[1].y + p[2].y + p[3].y;
    }
}

// ---- safety-net fallback (ws too small): dense branchy loops, inline FC ----
__global__ __launch_bounds__(512)
void dgru_raw(const float* __restrict__ x,
              const float* __restrict__ wih0, const float* __restrict__ whh0,
              const float* __restrict__ wih1, const float* __restrict__ whh1,
              const float* __restrict__ bih0, const float* __restrict__ bhh0,
              const float* __restrict__ bih1, const float* __restrict__ bhh1,
              const float* __restrict__ wfc,  const float* __restrict__ bfc,
              float* __restrict__ out) {
    __shared__ float s_dx0[8];
    __shared__ float s_xp0[8];
    __shared__ float s_dh0[HID];
    __shared__ float s_dx1[HID];
    __shared__ float s_dh1[HID];
    __shared__ float s_part[16];

    const int j = threadIdx.x;
    const int bq = blockIdx.x;
    float h0 = 0.f, h0p = 0.f, xp1 = 0.f, h1 = 0.f, h1p = 0.f;
    float cr0 = bih0[j] + bhh0[j];
    float cz0 = bih0[HID + j] + bhh0[HID + j];
    float cn0 = bih0[2*HID + j];
    float cnh0 = bhh0[2*HID + j];
    float cr1 = bih1[j] + bhh1[j];
    float cz1 = bih1[HID + j] + bhh1[HID + j];
    float cn1 = bih1[2*HID + j];
    float cnh1 = bhh1[2*HID + j];
    if (j < 8) { s_xp0[j] = 0.f; s_dx0[j] = 0.f; }
    const float wfc0 = wfc[j], wfc1 = wfc[HID + j];
    __syncthreads();

    for (int t = 0; t < NT; ++t) {
        float d = h0 - h0p;
        if (fabsf(d) < THH) d = 0.f; else h0p = h0;
        s_dh0[j] = d;
        if (j < 6) {
            float iv = x[(bq * NT + t) * 2 + 0];
            float qv = x[(bq * NT + t) * 2 + 1];
            float amp = sqrtf(iv * iv + qv * qv);
            float f;
            if      (j == 0) f = iv;
            else if (j == 1) f = qv;
            else if (j == 2) f = amp;
            else if (j == 3) f = amp * amp * amp;
            else if (j == 4) f = qv / amp;
            else             f = iv / amp;
            float dx = f - s_xp0[j];
            if (fabsf(dx) < THX) dx = 0.f; else s_xp0[j] = f;
            s_dx0[j] = dx;
        }
        __syncthreads();
        {
            float ar = cr0, az = cz0, an = cn0, anh = cnh0;
            #pragma unroll
            for (int f = 0; f < 6; ++f) {
                float dv = s_dx0[f];
                ar += dv * wih0[j * 6 + f];
                az += dv * wih0[(HID + j) * 6 + f];
                an += dv * wih0[(2*HID + j) * 6 + f];
            }
            for (int k = 0; k < HID; ++k) {
                float dv = s_dh0[k];
                if (dv != 0.f) {
                    ar  += dv * whh0[j * HID + k];
                    az  += dv * whh0[(HID + j) * HID + k];
                    anh += dv * whh0[(2*HID + j) * HID + k];
                }
            }
            cr0 = ar; cz0 = az; cn0 = an; cnh0 = anh;
            float r = 1.f / (1.f + expf(-ar));
            float z = 1.f / (1.f + expf(-az));
            float n = tanhf(an + r * anh);
            h0 = (1.f - z) * n + z * h0;
        }
        float dxv = h0 - xp1;
        if (fabsf(dxv) < THX) dxv = 0.f; else xp1 = h0;
        s_dx1[j] = dxv;
        float dhv = h1 - h1p;
        if (fabsf(dhv) < THH) dhv = 0.f; else h1p = h1;
        s_dh1[j] = dhv;
        __syncthreads();
        {
            float ar = cr1, az = cz1, an = cn1, anh = cnh1;
            for (int k = 0; k < HID; ++k) {
                float dv = s_dx1[k];
                if (dv != 0.f) {
                    ar += dv * wih1[j * HID + k];
                    az += dv * wih1[(HID + j) * HID + k];
                    an += dv * wih1[(2*HID + j) * HID + k];
                }
            }
            for (int k = 0; k < HID; ++k) {
                float dv = s_dh1[k];
                if (dv != 0.f) {
                    ar  += dv * whh1[j * HID + k];
                    az  += dv * whh1[(HID + j) * HID + k];
                    anh += dv * whh1[(2*HID + j) * HID + k];
                }
            }
            cr1 = ar; cz1 = az; cn1 = an; cnh1 = anh;
            float r = 1.f / (1.f + expf(-ar));
            float z = 1.f / (1.f + expf(-az));
            float n = tanhf(an + r * anh);
            h1 = (1.f - z) * n + z * h1;
        }
        float p0 = h1 * wfc0, p1 = h1 * wfc1;
        #pragma unroll
        for (int off = 32; off > 0; off >>= 1) {
            p0 += __shfl_down(p0, off, 64);
            p1 += __shfl_down(p1, off, 64);
        }
        if ((j & 63) == 0) { s_part[(j >> 6) * 2] = p0; s_part[(j >> 6) * 2 + 1] = p1; }
        __syncthreads();
        if (j == 0) {
            float o0 = bfc[0], o1 = bfc[1];
            #pragma unroll
            for (int w = 0; w < 8; ++w) { o0 += s_part[w * 2]; o1 += s_part[w * 2 + 1]; }
            out[(bq * NT + t) * 2 + 0] = o0;
            out[(bq * NT + t) * 2 + 1] = o1;
        }
    }
}

extern "C" void kernel_launch(void* const* d_in, const int* in_sizes, int n_in,
                              void* d_out, int out_size, void* d_ws, size_t ws_size,
                              hipStream_t stream) {
    const float* x    = (const float*)d_in[0];
    // d_in[1] = h_0 : reference zero-inits h, input unused
    const float* wih0 = (const float*)d_in[2];
    const float* whh0 = (const float*)d_in[3];
    const float* bih0 = (const float*)d_in[4];
    const float* bhh0 = (const float*)d_in[5];
    const float* wih1 = (const float*)d_in[6];
    const float* whh1 = (const float*)d_in[7];
    const float* bih1 = (const float*)d_in[8];
    const float* bhh1 = (const float*)d_in[9];
    const float* wfc  = (const float*)d_in[10];
    const float* bfc  = (const float*)d_in[11];
    float* out = (float*)d_out;

    const size_t MAT3    = (size_t)HID * 1536 * sizeof(float);      // 3 MiB each
    const size_t o_ih0   = 0;                                        // 36,864 B
    const size_t o_hh0   = 6 * 1536 * sizeof(float);
    const size_t o_ih1   = o_hh0 + MAT3;
    const size_t o_hh1   = o_ih1 + MAT3;
    const size_t o_pan   = o_hh1 + MAT3;
    const size_t PAN_B   = (size_t)4 * NG * 4 * 3 * 512 * 4;         // 1.5 MiB
    const size_t o_tags  = o_pan + PAN_B;
    const size_t o_fc    = o_tags + 4096;                            // tags padded
    const size_t FCB     = (size_t)NB * NT * 4 * 2 * sizeof(float);  // 2 MiB
    const size_t need    = o_fc + FCB;                               // ~12.6 MiB

    if (ws_size >= need) {
        float* wt_ih0 = (float*)((char*)d_ws + o_ih0);
        float* wt_hh0 = (float*)((char*)d_ws + o_hh0);
        float* wt_ih1 = (float*)((char*)d_ws + o_ih1);
        float* wt_hh1 = (float*)((char*)d_ws + o_hh1);
        float* g_pan  = (float*)((char*)d_ws + o_pan);
        int*   g_tags = (int*)((char*)d_ws + o_tags);
        float* g_fc   = (float*)((char*)d_ws + o_fc);

        pack_ih0<<<(6 * HID + 255) / 256, 256, 0, stream>>>(wih0, wt_ih0);
        pack_h3<<<(HID * HID + 255) / 256, 256, 0, stream>>>(whh0, wt_hh0);
        pack_h3<<<(HID * HID + 255) / 256, 256, 0, stream>>>(wih1, wt_ih1);
        pack_h3<<<(HID * HID + 255) / 256, 256, 0, stream>>>(whh1, wt_hh1);
        init_ws<<<(4 * NG * 4 * 3 * 512 + 1023) / 1024, 1024, 0, stream>>>(g_pan, g_tags);
        dgru_d<<<NG * 4, 1024, 0, stream>>>(x, wt_ih0, wt_hh0, wt_ih1, wt_hh1,
                                            bih0, bhh0, bih1, bhh1, wfc,
                                            g_pan, g_tags, g_fc);
        fc_reduce<<<(NB * NT + 255) / 256, 256, 0, stream>>>(g_fc, bfc, out);
    } else {
        dgru_raw<<<NB, HID, 0, stream>>>(x, wih0, whh0, wih1, whh1,
                                         bih0, bhh0, bih1, bhh1, wfc, bfc, out);
    }
}

// Round 19
// 24424.762 us; speedup vs baseline: 2.3901x; 2.3901x over previous
//
#include <hip/hip_runtime.h>

#define HID 512
#define NB  64
#define NT  1024
#define THX 0.1f
#define THH 0.05f
#define NP  32     // batch pairs
#define NE  8      // unit eighths (64 units each)

// ---- prep: pack W_ih_l0 [1536][6] f32 -> [6][512]{r,z,n} float3 ----
__global__ void pack_ih0(const float* __restrict__ src, float* __restrict__ dst) {
    int idx = blockIdx.x * blockDim.x + threadIdx.x;
    if (idx < 6 * HID) {
        int f = idx / HID, j = idx % HID;
        dst[f * 1536 + j * 3 + 0] = src[(0 * HID + j) * 6 + f];
        dst[f * 1536 + j * 3 + 1] = src[(1 * HID + j) * 6 + f];
        dst[f * 1536 + j * 3 + 2] = src[(2 * HID + j) * 6 + f];
    }
}

// ---- prep: pack a [1536][512] f32 matrix -> [512(k)][512(j)]{r,z,n|nh} ----
__global__ void pack_h3(const float* __restrict__ src, float* __restrict__ dst) {
    int idx = blockIdx.x * blockDim.x + threadIdx.x;
    if (idx < HID * HID) {
        int k = idx / HID, j = idx % HID;
        dst[k * 1536 + j * 3 + 0] = src[(0 * HID + j) * HID + k];
        dst[k * 1536 + j * 3 + 1] = src[(1 * HID + j) * HID + k];
        dst[k * 1536 + j * 3 + 2] = src[(2 * HID + j) * HID + k];
    }
}

// ---- init: zero tag words (tag 0 == expected at t=0, counts 0) ----
__global__ void init_ws(int* __restrict__ tags) {
    int i = blockIdx.x * blockDim.x + threadIdx.x;
    if (i < 4 * NP * NE) tags[i] = 0;
}

// list region: kind {0=dh0,1=dx1,2=dh1}, 4-deep slot, pair, eighth; 64 uint4 each
__device__ __forceinline__ int lofs4(int kind, int slot, int p, int e) {
    return (((kind * 4 + slot) * NP + p) * NE + e) * 64;   // uint4 units
}
__device__ __forceinline__ int tdx(int slot, int p, int e) {
    return (slot * NP + p) * NE + e;
}

// ---- coherent RELAXED ops only (r17: no release -> no L2 flush storms) ----
__device__ __forceinline__ int ld_tag(const int* p) {
    return __hip_atomic_load(p, __ATOMIC_RELAXED, __HIP_MEMORY_SCOPE_AGENT);
}
__device__ __forceinline__ uint2 ld_ent(const uint2* p) {
    unsigned long long r = __hip_atomic_load((const unsigned long long*)p,
                             __ATOMIC_RELAXED, __HIP_MEMORY_SCOPE_AGENT);
    return make_uint2((unsigned)r, (unsigned)(r >> 32));
}
__device__ __forceinline__ void st_ent(uint2* p, unsigned a, unsigned b) {
    unsigned long long r = (unsigned long long)a | ((unsigned long long)b << 32);
    __hip_atomic_store((unsigned long long*)p, r,
                       __ATOMIC_RELAXED, __HIP_MEMORY_SCOPE_AGENT);
}
__device__ __forceinline__ void st_tag(int* p, int v) {
    __hip_atomic_store(p, v, __ATOMIC_RELAXED, __HIP_MEMORY_SCOPE_AGENT);
}

// ---- depth-8 pipelined PAIR MAC, stride-16 union entries ----
// Entry (uint4): .x = koff bytes (k*6144), .y = dv batch0, .z = dv batch1.
// ONE float3 weight load serves 6 fmas (3 gates x 2 batches) -> halves L2
// weight traffic vs r17. Zeros in .y/.z are exact +0 adds (union list).
// m = n/16 per slot, multiple of 8 (n multiple of 128, n<=512).
__device__ __forceinline__ void mac2(const uint4* __restrict__ sl, int m,
                                     const char* __restrict__ cb,
                                     float& r0, float& r1, float& z0, float& z1,
                                     float& x0, float& x1) {
    if (m <= 0) return;
    float  a0,a1,a2,a3,a4,a5,a6,a7;     // dv batch0 per stage
    float  b0,b1,b2,b3,b4,b5,b6,b7;     // dv batch1
    float3 w0,w1,w2,w3,w4,w5,w6,w7;
#define PISS(S, J) { uint4 e_ = sl[16 * (J)]; \
    a##S = __uint_as_float(e_.y); b##S = __uint_as_float(e_.z); \
    w##S = *(const float3*)(cb + e_.x); }
#define PCON(S, JN, MORE) { float3 W_ = w##S; float A_ = a##S, B_ = b##S; \
    if (MORE) PISS(S, (JN)) \
    r0 += A_ * W_.x; r1 += B_ * W_.x; \
    z0 += A_ * W_.y; z1 += B_ * W_.y; \
    x0 += A_ * W_.z; x1 += B_ * W_.z; }
    PISS(0,0) PISS(1,1) PISS(2,2) PISS(3,3)
    PISS(4,4) PISS(5,5) PISS(6,6) PISS(7,7)
    #pragma unroll 1
    for (int j = 0; j < m; j += 8) {
        const int jn = j + 8;
        const bool mo = jn < m;
        PCON(0,jn+0,mo) PCON(1,jn+1,mo) PCON(2,jn+2,mo) PCON(3,jn+3,mo)
        PCON(4,jn+4,mo) PCON(5,jn+5,mo) PCON(6,jn+6,mo) PCON(7,jn+7,mo)
    }
#undef PISS
#undef PCON
}

// ---- main kernel: 256 WGs = 32 batch-pairs x 8 unit-eighths, both layers --
// 1024 thr = 16 slots x 64 units. wgid%8 = e -> each XCD caches only eighth-e
// weight slices (1.2 MB, L2-resident). r17 sync verbatim (relaxed + tag).
__global__ __launch_bounds__(1024, 4)
void dgru_p2(const float* __restrict__ x,
             const float* __restrict__ wih0p,   // [6][512] float3
             const float* __restrict__ whh0p,   // [512][512] float3 (r,z,nh)
             const float* __restrict__ wih1p,   // (r,z,n)
             const float* __restrict__ whh1p,   // (r,z,nh)
             const float* __restrict__ bih0, const float* __restrict__ bhh0,
             const float* __restrict__ bih1, const float* __restrict__ bhh1,
             const float* __restrict__ wfc,
             uint4* __restrict__ lists4, int* __restrict__ tags,
             float* __restrict__ ws_fc) {
    __shared__ float    s_x2[2][2 * NT];           // 16 KB
    __shared__ float    s_dx0[2][8];
    __shared__ float    s_xp0[2][8];
    __shared__ unsigned s_cw[NE];
    __shared__ uint4    s_lA[512], s_lB[512], s_lC[512];  // 24 KB
    __shared__ float    s_pp[16][18][64];          // 73.7 KB slot partials
    __shared__ float    s_ex[3][2][64];            // delta exchange 1.5 KB
    __shared__ int      s_cnt[3];

    const int wgid = blockIdx.x;
    const int p    = wgid >> 3;
    const int e    = wgid & 7;
    const int tid  = threadIdx.x;
    const int lane = tid & 63;
    const int wave = tid >> 6;        // 0..15 == MAC slot (wave-uniform)
    const int u    = tid & 63;
    const int uu   = e * 64 + u;      // this thread's output unit / column
    const int b2   = wave & 1;        // batch-in-pair for unit threads (tid<128)
    const int colbyte = uu * 12;

    // unit-thread state (tid<128): per (b2, uu), batch = p*2+b2
    float h0=0.f, h0p=0.f, xp1=0.f, h1=0.f, h1p=0.f;
    float cr0=0.f, cz0=0.f, cn0=0.f, cnh0=0.f;
    float cr1=0.f, cz1=0.f, cn1=0.f, cnh1=0.f;
    float wf0=0.f, wf1=0.f;
    if (tid < 128) {
        cr0  = bih0[uu]         + bhh0[uu];
        cz0  = bih0[HID + uu]   + bhh0[HID + uu];
        cn0  = bih0[2*HID + uu];
        cnh0 = bhh0[2*HID + uu];
        cr1  = bih1[uu]         + bhh1[uu];
        cz1  = bih1[HID + uu]   + bhh1[HID + uu];
        cn1  = bih1[2*HID + uu];
        cnh1 = bhh1[2*HID + uu];
        wf0 = wfc[uu]; wf1 = wfc[HID + uu];
    }

    const char* cbH0 = (const char*)whh0p + colbyte;
    const char* cbI1 = (const char*)wih1p + colbyte;
    const char* cbH1 = (const char*)whh1p + colbyte;

    for (int i = tid; i < 2 * 2 * NT; i += 1024) {
        int bb = i >> 11, idx = i & (2 * NT - 1);
        s_x2[bb][idx] = x[(size_t)(p * 2 + bb) * 2 * NT + idx];
    }
    if (tid < 16) { s_xp0[tid >> 3][tid & 7] = 0.f; s_dx0[tid >> 3][tid & 7] = 0.f; }
    __syncthreads();

    for (int t = 0; t <= NT; ++t) {
        const int slot_r = (t + 3) & 3, slot_w = t & 3;
        // ===== S0: poll the 8 eighth tag-words, broadcast =================
        if (tid < NE) {
            const unsigned expct = (unsigned)(t & 0xFF);
            const int* tp = tags + tdx(slot_r, p, tid);
            unsigned v;
            while (((v = (unsigned)ld_tag(tp)) >> 24) != expct)
                __builtin_amdgcn_s_sleep(2);
            s_cw[tid] = v;
        }
        __syncthreads();                                   // S0
        int cA[NE], cB[NE], cC[NE];
        int nA = 0, nB = 0, nC = 0;
        #pragma unroll
        for (int ee = 0; ee < NE; ++ee) {
            unsigned v = s_cw[ee];
            cA[ee] = (int)(v & 0xFF);
            cB[ee] = (int)((v >> 8) & 0xFF);
            cC[ee] = (int)((v >> 16) & 0xFF);
            nA += cA[ee]; nB += cB[ee]; nC += cC[ee];
        }
        const int nAp = (nA + 127) & ~127;
        const int nBp = (nB + 127) & ~127;
        const int nCp = (nC + 127) & ~127;

        // ===== stage: union lists -> LDS (2 x 8B reads per 16B entry) =====
        if (t < NT) {
            if (tid < nAp) {
                if (tid < nA) {
                    int xx = tid, ee = 0;
                    while (xx >= cA[ee]) { xx -= cA[ee]; ++ee; }
                    const uint2* gp = (const uint2*)(lists4 + lofs4(0, slot_r, p, ee) + xx);
                    uint2 lo = ld_ent(gp), hi = ld_ent(gp + 1);
                    s_lA[tid] = make_uint4(lo.x, lo.y, hi.x, hi.y);
                } else s_lA[tid] = make_uint4(0u, 0u, 0u, 0u);
            }
            if (tid < 16) {
                int bb = tid >> 3, f = tid & 7;
                if (f < 6) {
                    float iv = s_x2[bb][2 * t], qv = s_x2[bb][2 * t + 1];
                    float amp = sqrtf(iv * iv + qv * qv);
                    float fv;
                    if      (f == 0) fv = iv;
                    else if (f == 1) fv = qv;
                    else if (f == 2) fv = amp;
                    else if (f == 3) fv = amp * amp * amp;
                    else if (f == 4) fv = qv / amp;
                    else             fv = iv / amp;
                    float dx = fv - s_xp0[bb][f];
                    if (fabsf(dx) < THX) dx = 0.f; else s_xp0[bb][f] = fv;
                    s_dx0[bb][f] = dx;
                }
            }
        }
        if (t > 0) {
            if (tid < nBp) {
                if (tid < nB) {
                    int xx = tid, ee = 0;
                    while (xx >= cB[ee]) { xx -= cB[ee]; ++ee; }
                    const uint2* gp = (const uint2*)(lists4 + lofs4(1, slot_r, p, ee) + xx);
                    uint2 lo = ld_ent(gp), hi = ld_ent(gp + 1);
                    s_lB[tid] = make_uint4(lo.x, lo.y, hi.x, hi.y);
                } else s_lB[tid] = make_uint4(0u, 0u, 0u, 0u);
            }
            if (tid < nCp) {
                if (tid < nC) {
                    int xx = tid, ee = 0;
                    while (xx >= cC[ee]) { xx -= cC[ee]; ++ee; }
                    const uint2* gp = (const uint2*)(lists4 + lofs4(2, slot_r, p, ee) + xx);
                    uint2 lo = ld_ent(gp), hi = ld_ent(gp + 1);
                    s_lC[tid] = make_uint4(lo.x, lo.y, hi.x, hi.y);
                } else s_lC[tid] = make_uint4(0u, 0u, 0u, 0u);
            }
        }
        __syncthreads();                                   // S1

        // ===== MAC phase: all 16 slots, both layers, no intermediate bars ==
        {
            float* pp = &s_pp[wave][0][u];
            if (t < NT) {
                float q0=0,q1=0,q2=0,q3=0,q4=0,q5=0;
                mac2(s_lA + wave, nAp >> 4, cbH0, q0,q1,q2,q3,q4,q5);
                pp[0] = q0; pp[64] = q1; pp[2*64] = q2;
                pp[3*64] = q3; pp[4*64] = q4; pp[5*64] = q5;
            }
            if (t > 0) {
                float q0=0,q1=0,q2=0,q3=0,q4=0,q5=0;
                mac2(s_lB + wave, nBp >> 4, cbI1, q0,q1,q2,q3,q4,q5);
                pp[6*64] = q0; pp[7*64] = q1; pp[8*64] = q2;
                pp[9*64] = q3; pp[10*64] = q4; pp[11*64] = q5;
                float s0=0,s1=0,s2=0,s3=0,s4=0,s5=0;
                mac2(s_lC + wave, nCp >> 4, cbH1, s0,s1,s2,s3,s4,s5);
                pp[12*64] = s0; pp[13*64] = s1; pp[14*64] = s2;
                pp[15*64] = s3; pp[16*64] = s4; pp[17*64] = s5;
            }
        }
        __syncthreads();                                   // S2

        // ===== unit phase (tid<128): merge 16 slots, gates, deltas, FC ====
        if (tid < 128) {
            if (t < NT) {
                float mhR = 0.f, mhZ = 0.f, mhN = 0.f;
                #pragma unroll
                for (int s = 0; s < 16; ++s) {
                    mhR += s_pp[s][0 + b2][u];
                    mhZ += s_pp[s][2 + b2][u];
                    mhN += s_pp[s][4 + b2][u];
                }
                float iR = 0.f, iZ = 0.f, iN = 0.f;
                #pragma unroll
                for (int f = 0; f < 6; ++f) {              // dv==0 adds exact +0
                    float dv = s_dx0[b2][f];
                    const float* wr = wih0p + f * 1536 + uu * 3;
                    iR += dv * wr[0]; iZ += dv * wr[1]; iN += dv * wr[2];
                }
                float ar  = cr0 + iR + mhR;                // carry + mac_x + mac_h
                float az  = cz0 + iZ + mhZ;
                float an  = cn0 + iN;
                float anh = cnh0 + mhN;
                cr0 = ar; cz0 = az; cn0 = an; cnh0 = anh;
                float r = 1.f / (1.f + expf(-ar));
                float z = 1.f / (1.f + expf(-az));
                float n = tanhf(an + r * anh);
                h0 = (1.f - z) * n + z * h0;
                float dA = h0 - h0p; if (fabsf(dA) < THH) dA = 0.f; else h0p = h0;
                float dB = h0 - xp1; if (fabsf(dB) < THX) dB = 0.f; else xp1 = h0;
                s_ex[0][b2][u] = dA;
                s_ex[1][b2][u] = dB;
            }
            if (t > 0) {
                float xiR = 0.f, xiZ = 0.f, xiN = 0.f;
                float mhR = 0.f, mhZ = 0.f, mhN = 0.f;
                #pragma unroll
                for (int s = 0; s < 16; ++s) {
                    xiR += s_pp[s][6 + b2][u];
                    xiZ += s_pp[s][8 + b2][u];
                    xiN += s_pp[s][10 + b2][u];
                    mhR += s_pp[s][12 + b2][u];
                    mhZ += s_pp[s][14 + b2][u];
                    mhN += s_pp[s][16 + b2][u];
                }
                float ar  = cr1 + xiR + mhR;
                float az  = cz1 + xiZ + mhZ;
                float an  = cn1 + xiN;
                float anh = cnh1 + mhN;
                cr1 = ar; cz1 = az; cn1 = an; cnh1 = anh;
                float r = 1.f / (1.f + expf(-ar));
                float z = 1.f / (1.f + expf(-az));
                float n = tanhf(an + r * anh);
                h1 = (1.f - z) * n + z * h1;
                float p0 = h1 * wf0, p1 = h1 * wf1;
                #pragma unroll
                for (int off = 32; off > 0; off >>= 1) {
                    p0 += __shfl_down(p0, off, 64);
                    p1 += __shfl_down(p1, off, 64);
                }
                if (lane == 0) {
                    float2* dst = (float2*)(ws_fc +
                        (((size_t)(p * 2 + b2) * NT + (t - 1)) * NE + e) * 2);
                    *dst = make_float2(p0, p1);
                }
            }
            if (t < NT) {
                float dC = h1 - h1p; if (fabsf(dC) < THH) dC = 0.f; else h1p = h1;
                s_ex[2][b2][u] = dC;
            }
        }
        __syncthreads();                                   // S3

        // ===== publish: waves 0..2 compact union lists (64 units = 1 wave) =
        if (t < NT && wave < 3) {
            const int kind = wave;
            float d0 = s_ex[kind][0][lane];
            float d1 = s_ex[kind][1][lane];
            bool nz = (d0 != 0.f) || (d1 != 0.f);
            unsigned long long m = __ballot(nz);
            if (nz) {
                int pos = __popcll(m & ((1ull << lane) - 1));
                uint2* dst = (uint2*)(lists4 + lofs4(kind, slot_w, p, e) + pos);
                st_ent(dst,     (unsigned)((e * 64 + lane) * 6144),
                                __float_as_uint(d0));
                st_ent(dst + 1, __float_as_uint(d1), 0u);
            }
            if (lane == 0) s_cnt[kind] = __popcll(m);
        }
        __syncthreads();     // S4: vmcnt(0) drain -> entry stores complete at LLC

        if (t < NT && tid == 0) {
            unsigned word = ((unsigned)((t + 1) & 0xFF) << 24)
                          | ((unsigned)s_cnt[2] << 16)
                          | ((unsigned)s_cnt[1] << 8)
                          |  (unsigned)s_cnt[0];
            st_tag(tags + tdx(slot_w, p, e), (int)word);
        }
    }
}

// ---- epilogue: deterministic FC reduction over 8 eighths (ascending) ----
__global__ void fc_reduce(const float* __restrict__ ws_fc,
                          const float* __restrict__ bfc,
                          float* __restrict__ out) {
    int idx = blockIdx.x * blockDim.x + threadIdx.x;   // (b*NT + t)
    if (idx < NB * NT) {
        const float2* p = (const float2*)(ws_fc + (size_t)idx * 16);
        float o0 = bfc[0], o1 = bfc[1];
        #pragma unroll
        for (int e = 0; e < NE; ++e) { o0 += p[e].x; o1 += p[e].y; }
        out[idx * 2 + 0] = o0;
        out[idx * 2 + 1] = o1;
    }
}

// ---- safety-net fallback (ws too small): dense branchy loops, inline FC ----
__global__ __launch_bounds__(512)
void dgru_raw(const float* __restrict__ x,
              const float* __restrict__ wih0, const float* __restrict__ whh0,
              const float* __restrict__ wih1, const float* __restrict__ whh1,
              const float* __restrict__ bih0, const float* __restrict__ bhh0,
              const float* __restrict__ bih1, const float* __restrict__ bhh1,
              const float* __restrict__ wfc,  const float* __restrict__ bfc,
              float* __restrict__ out) {
    __shared__ float s_dx0[8];
    __shared__ float s_xp0[8];
    __shared__ float s_dh0[HID];
    __shared__ float s_dx1[HID];
    __shared__ float s_dh1[HID];
    __shared__ float s_part[16];

    const int j = threadIdx.x;
    const int bq = blockIdx.x;
    float h0 = 0.f, h0p = 0.f, xp1 = 0.f, h1 = 0.f, h1p = 0.f;
    float cr0 = bih0[j] + bhh0[j];
    float cz0 = bih0[HID + j] + bhh0[HID + j];
    float cn0 = bih0[2*HID + j];
    float cnh0 = bhh0[2*HID + j];
    float cr1 = bih1[j] + bhh1[j];
    float cz1 = bih1[HID + j] + bhh1[HID + j];
    float cn1 = bih1[2*HID + j];
    float cnh1 = bhh1[2*HID + j];
    if (j < 8) { s_xp0[j] = 0.f; s_dx0[j] = 0.f; }
    const float wfc0 = wfc[j], wfc1 = wfc[HID + j];
    __syncthreads();

    for (int t = 0; t < NT; ++t) {
        float d = h0 - h0p;
        if (fabsf(d) < THH) d = 0.f; else h0p = h0;
        s_dh0[j] = d;
        if (j < 6) {
            float iv = x[(bq * NT + t) * 2 + 0];
            float qv = x[(bq * NT + t) * 2 + 1];
            float amp = sqrtf(iv * iv + qv * qv);
            float f;
            if      (j == 0) f = iv;
            else if (j == 1) f = qv;
            else if (j == 2) f = amp;
            else if (j == 3) f = amp * amp * amp;
            else if (j == 4) f = qv / amp;
            else             f = iv / amp;
            float dx = f - s_xp0[j];
            if (fabsf(dx) < THX) dx = 0.f; else s_xp0[j] = f;
            s_dx0[j] = dx;
        }
        __syncthreads();
        {
            float ar = cr0, az = cz0, an = cn0, anh = cnh0;
            #pragma unroll
            for (int f = 0; f < 6; ++f) {
                float dv = s_dx0[f];
                ar += dv * wih0[j * 6 + f];
                az += dv * wih0[(HID + j) * 6 + f];
                an += dv * wih0[(2*HID + j) * 6 + f];
            }
            for (int k = 0; k < HID; ++k) {
                float dv = s_dh0[k];
                if (dv != 0.f) {
                    ar  += dv * whh0[j * HID + k];
                    az  += dv * whh0[(HID + j) * HID + k];
                    anh += dv * whh0[(2*HID + j) * HID + k];
                }
            }
            cr0 = ar; cz0 = az; cn0 = an; cnh0 = anh;
            float r = 1.f / (1.f + expf(-ar));
            float z = 1.f / (1.f + expf(-az));
            float n = tanhf(an + r * anh);
            h0 = (1.f - z) * n + z * h0;
        }
        float dxv = h0 - xp1;
        if (fabsf(dxv) < THX) dxv = 0.f; else xp1 = h0;
        s_dx1[j] = dxv;
        float dhv = h1 - h1p;
        if (fabsf(dhv) < THH) dhv = 0.f; else h1p = h1;
        s_dh1[j] = dhv;
        __syncthreads();
        {
            float ar = cr1, az = cz1, an = cn1, anh = cnh1;
            for (int k = 0; k < HID; ++k) {
                float dv = s_dx1[k];
                if (dv != 0.f) {
                    ar += dv * wih1[j * HID + k];
                    az += dv * wih1[(HID + j) * HID + k];
                    an += dv * wih1[(2*HID + j) * HID + k];
                }
            }
            for (int k = 0; k < HID; ++k) {
                float dv = s_dh1[k];
                if (dv != 0.f) {
                    ar  += dv * whh1[j * HID + k];
                    az  += dv * whh1[(HID + j) * HID + k];
                    anh += dv * whh1[(2*HID + j) * HID + k];
                }
            }
            cr1 = ar; cz1 = az; cn1 = an; cnh1 = anh;
            float r = 1.f / (1.f + expf(-ar));
            float z = 1.f / (1.f + expf(-az));
            float n = tanhf(an + r * anh);
            h1 = (1.f - z) * n + z * h1;
        }
        float p0 = h1 * wfc0, p1 = h1 * wfc1;
        #pragma unroll
        for (int off = 32; off > 0; off >>= 1) {
            p0 += __shfl_down(p0, off, 64);
            p1 += __shfl_down(p1, off, 64);
        }
        if ((j & 63) == 0) { s_part[(j >> 6) * 2] = p0; s_part[(j >> 6) * 2 + 1] = p1; }
        __syncthreads();
        if (j == 0) {
            float o0 = bfc[0], o1 = bfc[1];
            #pragma unroll
            for (int w = 0; w < 8; ++w) { o0 += s_part[w * 2]; o1 += s_part[w * 2 + 1]; }
            out[(bq * NT + t) * 2 + 0] = o0;
            out[(bq * NT + t) * 2 + 1] = o1;
        }
    }
}

extern "C" void kernel_launch(void* const* d_in, const int* in_sizes, int n_in,
                              void* d_out, int out_size, void* d_ws, size_t ws_size,
                              hipStream_t stream) {
    const float* x    = (const float*)d_in[0];
    // d_in[1] = h_0 : reference zero-inits h, input unused
    const float* wih0 = (const float*)d_in[2];
    const float* whh0 = (const float*)d_in[3];
    const float* bih0 = (const float*)d_in[4];
    const float* bhh0 = (const float*)d_in[5];
    const float* wih1 = (const float*)d_in[6];
    const float* whh1 = (const float*)d_in[7];
    const float* bih1 = (const float*)d_in[8];
    const float* bhh1 = (const float*)d_in[9];
    const float* wfc  = (const float*)d_in[10];
    const float* bfc  = (const float*)d_in[11];
    float* out = (float*)d_out;

    const size_t MAT3    = (size_t)HID * 1536 * sizeof(float);      // 3 MiB each
    const size_t o_ih0   = 0;                                        // 36,864 B
    const size_t o_hh0   = 6 * 1536 * sizeof(float);
    const size_t o_ih1   = o_hh0 + MAT3;
    const size_t o_hh1   = o_ih1 + MAT3;
    const size_t o_lists = o_hh1 + MAT3;
    const size_t LISTS_B = (size_t)3 * 4 * NP * NE * 64 * 16;        // 3 MiB
    const size_t o_tags  = o_lists + LISTS_B;
    const size_t o_fc    = o_tags + (size_t)4 * NP * NE * sizeof(int);
    const size_t FCB     = (size_t)NB * NT * NE * 2 * sizeof(float); // 4 MiB
    const size_t need    = o_fc + FCB;                               // ~16.1 MiB

    if (ws_size >= need) {
        float* wt_ih0 = (float*)((char*)d_ws + o_ih0);
        float* wt_hh0 = (float*)((char*)d_ws + o_hh0);
        float* wt_ih1 = (float*)((char*)d_ws + o_ih1);
        float* wt_hh1 = (float*)((char*)d_ws + o_hh1);
        uint4* g_lists = (uint4*)((char*)d_ws + o_lists);
        int*   g_tags  = (int*)((char*)d_ws + o_tags);
        float* g_fc    = (float*)((char*)d_ws + o_fc);

        pack_ih0<<<(6 * HID + 255) / 256, 256, 0, stream>>>(wih0, wt_ih0);
        pack_h3<<<(HID * HID + 255) / 256, 256, 0, stream>>>(whh0, wt_hh0);
        pack_h3<<<(HID * HID + 255) / 256, 256, 0, stream>>>(wih1, wt_ih1);
        pack_h3<<<(HID * HID + 255) / 256, 256, 0, stream>>>(whh1, wt_hh1);
        init_ws<<<1, 1024, 0, stream>>>(g_tags);
        dgru_p2<<<NP * NE, 1024, 0, stream>>>(x, wt_ih0, wt_hh0, wt_ih1, wt_hh1,
                                              bih0, bhh0, bih1, bhh1, wfc,
                                              g_lists, g_tags, g_fc);
        fc_reduce<<<(NB * NT + 255) / 256, 256, 0, stream>>>(g_fc, bfc, out);
    } else {
        dgru_raw<<<NB, HID, 0, stream>>>(x, wih0, whh0, wih1, whh1,
                                         bih0, bhh0, bih1, bhh1, wfc, bfc, out);
    }
}

// Round 20
// 23504.831 us; speedup vs baseline: 2.4837x; 1.0391x over previous
//
#include <hip/hip_runtime.h>

#define HID 512
#define NB  64
#define NT  1024
#define THX 0.1f
#define THH 0.05f

// ---- prep: pack W_ih_l0 [1536][6] f32 -> [6][512]{r,z,n} float3 ----
__global__ void pack_ih0(const float* __restrict__ src, float* __restrict__ dst) {
    int idx = blockIdx.x * blockDim.x + threadIdx.x;
    if (idx < 6 * HID) {
        int f = idx / HID, j = idx % HID;
        dst[f * 1536 + j * 3 + 0] = src[(0 * HID + j) * 6 + f];
        dst[f * 1536 + j * 3 + 1] = src[(1 * HID + j) * 6 + f];
        dst[f * 1536 + j * 3 + 2] = src[(2 * HID + j) * 6 + f];
    }
}

// ---- prep: pack a [1536][512] f32 matrix -> [512(k)][512(j)]{r,z,n|nh} ----
__global__ void pack_h3(const float* __restrict__ src, float* __restrict__ dst) {
    int idx = blockIdx.x * blockDim.x + threadIdx.x;
    if (idx < HID * HID) {
        int k = idx / HID, j = idx % HID;
        dst[k * 1536 + j * 3 + 0] = src[(0 * HID + j) * HID + k];
        dst[k * 1536 + j * 3 + 1] = src[(1 * HID + j) * HID + k];
        dst[k * 1536 + j * 3 + 2] = src[(2 * HID + j) * HID + k];
    }
}

// ---- init: zero packed count words (tag 0 == expected at t=0) ----
__global__ void init_ws(int* __restrict__ cnts) {
    int i = blockIdx.x * blockDim.x + threadIdx.x;
    if (i < 4 * NB * 4) cnts[i] = 0;
}

// packed count word index: (slot4, batch, quarter)
__device__ __forceinline__ int widx(int slot, int b, int q) {
    return (slot * NB + b) * 4 + q;
}
// list region: kind {0=A dh0, 1=B dx1, 2=C dh1}, 4-deep slot, batch, quarter
__device__ __forceinline__ int lofs(int kind, int slot, int b, int q) {
    return (((kind * 4 + slot) * NB + b) * 4 + q) * 128;   // uint2 units
}

// ---- coherent RELAXED ops only (no release in the hot loop -> no per-step
// L2 writeback sweeps; r17's -22% came exactly from removing them) ----
__device__ __forceinline__ int ld_cnt(const int* p) {
    return __hip_atomic_load(p, __ATOMIC_RELAXED, __HIP_MEMORY_SCOPE_AGENT);
}
__device__ __forceinline__ uint2 ld_ent(const uint2* p) {
    unsigned long long r = __hip_atomic_load((const unsigned long long*)p,
                             __ATOMIC_RELAXED, __HIP_MEMORY_SCOPE_AGENT);
    return make_uint2((unsigned)r, (unsigned)(r >> 32));
}
__device__ __forceinline__ void st_ent(uint2* p, unsigned a, unsigned b) {
    unsigned long long r = (unsigned long long)a | ((unsigned long long)b << 32);
    __hip_atomic_store((unsigned long long*)p, r,
                       __ATOMIC_RELAXED, __HIP_MEMORY_SCOPE_AGENT);
}
__device__ __forceinline__ void st_cnt(int* p, int v) {
    __hip_atomic_store(p, v, __ATOMIC_RELAXED, __HIP_MEMORY_SCOPE_AGENT);
}

// ---- depth-8 pipelined slot MAC, stride-8 entries (r15-r17 proven) ----
// Slot s processes entries 8j+s; only ONE slot (2 waves of 128 units) loads
// each entry -> 2 VMEM instrs/entry (dwordx3, all 3 gate weights).
// m = n/8 per slot, multiple of 8 (n multiple of 64); pads (0,0) read row 0
// with v=0 -> exact +0. e.x = pre-multiplied byte offset k*6144.
__device__ __forceinline__ void mac3s(const uint2* __restrict__ sl, int m,
                                      const char* __restrict__ cb,
                                      float& a0, float& a1, float& a2) {
    if (m <= 0) return;
    float  v0, v1, v2, v3, v4, v5, v6, v7;
    float3 w0, w1, w2, w3, w4, w5, w6, w7;
#define PISS(S, J) { uint2 e_ = sl[8 * (J)]; v##S = __uint_as_float(e_.y); \
    w##S = *(const float3*)(cb + e_.x); }
#define PCON(S, JN, MORE) { float3 W_ = w##S; float V_ = v##S; \
    if (MORE) PISS(S, (JN)) \
    a0 += V_ * W_.x; a1 += V_ * W_.y; a2 += V_ * W_.z; }
    PISS(0,0) PISS(1,1) PISS(2,2) PISS(3,3)
    PISS(4,4) PISS(5,5) PISS(6,6) PISS(7,7)
    #pragma unroll 1
    for (int j = 0; j < m; j += 8) {
        const int jn = j + 8;
        const bool more = jn < m;
        PCON(0,jn+0,more) PCON(1,jn+1,more) PCON(2,jn+2,more) PCON(3,jn+3,more)
        PCON(4,jn+4,more) PCON(5,jn+5,more) PCON(6,jn+6,more) PCON(7,jn+7,more)
    }
#undef PISS
#undef PCON
}

// ---- main kernel: 256 WGs = 64 batches x 4 unit-quarters (both layers) ----
// r17 verbatim (best: 23.5 ms): lock-free tag sync, relaxed-only LLC ops,
// entry stores complete at LLC via the S4 vmcnt drain before the tag store.
// 4-deep rotation + mod-256 tag: skew bound 3 < 4 -> race-free.
__global__ __launch_bounds__(1024, 4)
void dgru_q(const float* __restrict__ x,
            const float* __restrict__ wih0p,   // [6][512] float3
            const float* __restrict__ whh0p,   // [512][512] float3
            const float* __restrict__ wih1p,
            const float* __restrict__ whh1p,
            const float* __restrict__ bih0, const float* __restrict__ bhh0,
            const float* __restrict__ bih1, const float* __restrict__ bhh1,
            const float* __restrict__ wfc,
            uint2* __restrict__ lists, int* __restrict__ cnts,
            float* __restrict__ ws_fc) {
    __shared__ float s_x[2 * NT];                  // 8 KB
    __shared__ float s_dx0[8];
    __shared__ float s_xp0[8];
    __shared__ unsigned s_cw[4];
    __shared__ uint2 s_lA[576], s_lB[576], s_lC[576];   // 13.5 KB
    __shared__ float s_pp[8][12][128];             // 48 KB slot partials
    __shared__ int   s_c1[2], s_c2[2], s_c3[2];
    __shared__ float s_fcp[2][2];

    const int wgid = blockIdx.x;
    const int bq   = wgid >> 2;
    const int q    = wgid & 3;
    const int tid  = threadIdx.x;
    const int lane = tid & 63;
    const int wave = tid >> 6;        // 0..15
    const int slot = tid >> 7;        // 0..7, wave-uniform
    const int u    = tid & 127;
    const int uu   = q * 128 + u;     // global unit id

    // carries + unit state for BOTH layers (tid<128 meaningful)
    float cr0 = 0.f, cz0 = 0.f, cn0 = 0.f, cnh0 = 0.f;
    float cr1 = 0.f, cz1 = 0.f, cn1 = 0.f, cnh1 = 0.f;
    float h0 = 0.f, h0p = 0.f, xp1 = 0.f, h1 = 0.f, h1p = 0.f;
    float wfc0 = 0.f, wfc1 = 0.f;
    if (tid < 128) {
        cr0  = bih0[uu]         + bhh0[uu];
        cz0  = bih0[HID + uu]   + bhh0[HID + uu];
        cn0  = bih0[2*HID + uu];
        cnh0 = bhh0[2*HID + uu];
        cr1  = bih1[uu]         + bhh1[uu];
        cz1  = bih1[HID + uu]   + bhh1[HID + uu];
        cn1  = bih1[2*HID + uu];
        cnh1 = bhh1[2*HID + uu];
        wfc0 = wfc[uu]; wfc1 = wfc[HID + uu];
    }

    // per-thread column bases (12 B per unit)
    const char* c_ih0 = (const char*)wih0p + uu * 12;
    const char* c_hh0 = (const char*)whh0p + uu * 12;
    const char* c_ih1 = (const char*)wih1p + uu * 12;
    const char* c_hh1 = (const char*)whh1p + uu * 12;

    for (int i = tid; i < 2 * NT; i += 1024) s_x[i] = x[bq * 2 * NT + i];
    if (tid < 8) { s_xp0[tid] = 0.f; s_dx0[tid] = 0.f; }
    __syncthreads();

    for (int t = 0; t <= NT; ++t) {
        const int slot_r = (t + 3) & 3;    // (t-1) mod 4: data published at t-1
        const int slot_w = t & 3;
        // ===== S0: poll the 4 quarter count-words (4 lanes), broadcast =====
        if (tid < 4) {
            const unsigned expct = (unsigned)(t & 0xFF);
            const int* wp = &cnts[widx(slot_r, bq, tid)];
            unsigned v;
            while (((v = (unsigned)ld_cnt(wp)) >> 24) != expct)
                __builtin_amdgcn_s_sleep(2);
            s_cw[tid] = v;
        }
        __syncthreads();                                     // S0
        int cA[4], cB[4], cC[4];
        int nA = 0, nB = 0, nC = 0;
        #pragma unroll
        for (int qq = 0; qq < 4; ++qq) {
            unsigned v = s_cw[qq];
            cA[qq] = (int)(v & 0xFF);
            cB[qq] = (int)((v >> 8) & 0xFF);
            cC[qq] = (int)((v >> 16) & 0xFF);
            nA += cA[qq]; nB += cB[qq]; nC += cC[qq];
        }
        const int nAp = (nA + 63) & ~63;
        const int nBp = (nB + 63) & ~63;
        const int nCp = (nC + 63) & ~63;

        // ===== stage phase: needed lists -> LDS (merged, k ascending) =====
        if (t < NT) {
            for (int i = tid; i < nAp; i += 1024) {
                if (i < nA) {
                    int xx = i, qq = 0;
                    while (xx >= cA[qq]) { xx -= cA[qq]; ++qq; }
                    s_lA[i] = ld_ent(lists + lofs(0, slot_r, bq, qq) + xx);
                } else s_lA[i] = make_uint2(0u, 0u);
            }
            if (tid < 6) {                        // input features, step t
                float iv = s_x[2 * t], qv = s_x[2 * t + 1];
                float amp = sqrtf(iv * iv + qv * qv);
                float f;
                if      (tid == 0) f = iv;
                else if (tid == 1) f = qv;
                else if (tid == 2) f = amp;
                else if (tid == 3) f = amp * amp * amp;
                else if (tid == 4) f = qv / amp;
                else               f = iv / amp;
                float dx = f - s_xp0[tid];
                if (fabsf(dx) < THX) dx = 0.f; else s_xp0[tid] = f;
                s_dx0[tid] = dx;
            }
        }
        if (t > 0) {
            for (int i = tid; i < nBp; i += 1024) {
                if (i < nB) {
                    int xx = i, qq = 0;
                    while (xx >= cB[qq]) { xx -= cB[qq]; ++qq; }
                    s_lB[i] = ld_ent(lists + lofs(1, slot_r, bq, qq) + xx);
                } else s_lB[i] = make_uint2(0u, 0u);
            }
            for (int i = tid; i < nCp; i += 1024) {
                if (i < nC) {
                    int xx = i, qq = 0;
                    while (xx >= cC[qq]) { xx -= cC[qq]; ++qq; }
                    s_lC[i] = ld_ent(lists + lofs(2, slot_r, bq, qq) + xx);
                } else s_lC[i] = make_uint2(0u, 0u);
            }
        }
        __syncthreads();                                     // S1

        // ===== MAC phase: slot-parallel over both layers ==================
        if (t < NT) {
            float hR = 0.f, hZ = 0.f, hNH = 0.f;
            mac3s(s_lA + slot, nAp >> 3, c_hh0, hR, hZ, hNH);
            s_pp[slot][0][u] = hR;
            s_pp[slot][1][u] = hZ;
            s_pp[slot][2][u] = hNH;
            if (slot == 0) {                      // dense ih0 (6 features)
                float iR = 0.f, iZ = 0.f, iN = 0.f;
                #pragma unroll
                for (int f = 0; f < 6; ++f) {     // dv==0 adds exact +0
                    float dv = s_dx0[f];
                    float3 w = *(const float3*)(c_ih0 + f * 6144);
                    iR += dv * w.x; iZ += dv * w.y; iN += dv * w.z;
                }
                s_pp[0][3][u] = iR;
                s_pp[0][4][u] = iZ;
                s_pp[0][5][u] = iN;
            }
        }
        if (t > 0) {
            float iR = 0.f, iZ = 0.f, iN = 0.f;
            float hR = 0.f, hZ = 0.f, hNH = 0.f;
            mac3s(s_lB + slot, nBp >> 3, c_ih1, iR, iZ, iN);
            mac3s(s_lC + slot, nCp >> 3, c_hh1, hR, hZ, hNH);
            s_pp[slot][6][u]  = iR;
            s_pp[slot][7][u]  = iZ;
            s_pp[slot][8][u]  = iN;
            s_pp[slot][9][u]  = hR;
            s_pp[slot][10][u] = hZ;
            s_pp[slot][11][u] = hNH;
        }
        __syncthreads();                                     // S2

        // ===== unit phase (tid<128): merge, gates, deltas, FC =============
        float dA = 0.f, dB = 0.f, dC = 0.f;
        bool nzA = false, nzB = false, nzC = false;
        unsigned long long mA = 0, mB = 0, mC = 0;
        if (tid < 128) {
            if (t < NT) {
                float mhR = 0.f, mhZ = 0.f, mhN = 0.f;
                #pragma unroll
                for (int s = 0; s < 8; ++s) {
                    mhR += s_pp[s][0][u]; mhZ += s_pp[s][1][u]; mhN += s_pp[s][2][u];
                }
                float ar  = cr0 + s_pp[0][3][u] + mhR;   // carry + mac_x + mac_h
                float az  = cz0 + s_pp[0][4][u] + mhZ;
                float an  = cn0 + s_pp[0][5][u];
                float anh = cnh0 + mhN;
                cr0 = ar; cz0 = az; cn0 = an; cnh0 = anh;
                float r = 1.f / (1.f + expf(-ar));
                float z = 1.f / (1.f + expf(-az));
                float n = tanhf(an + r * anh);
                h0 = (1.f - z) * n + z * h0;
                dA = h0 - h0p; if (fabsf(dA) < THH) dA = 0.f; else h0p = h0;
                dB = h0 - xp1; if (fabsf(dB) < THX) dB = 0.f; else xp1 = h0;
                nzA = dA != 0.f; nzB = dB != 0.f;
            }
            if (t > 0) {
                float xiR = 0.f, xiZ = 0.f, xiN = 0.f;
                float mhR = 0.f, mhZ = 0.f, mhN = 0.f;
                #pragma unroll
                for (int s = 0; s < 8; ++s) {
                    xiR += s_pp[s][6][u];  xiZ += s_pp[s][7][u];  xiN += s_pp[s][8][u];
                    mhR += s_pp[s][9][u];  mhZ += s_pp[s][10][u]; mhN += s_pp[s][11][u];
                }
                float ar  = cr1 + xiR + mhR;
                float az  = cz1 + xiZ + mhZ;
                float an  = cn1 + xiN;
                float anh = cnh1 + mhN;
                cr1 = ar; cz1 = az; cn1 = an; cnh1 = anh;
                float r = 1.f / (1.f + expf(-ar));
                float z = 1.f / (1.f + expf(-az));
                float n = tanhf(an + r * anh);
                h1 = (1.f - z) * n + z * h1;
                float p0 = h1 * wfc0, p1 = h1 * wfc1;
                #pragma unroll
                for (int off = 32; off > 0; off >>= 1) {
                    p0 += __shfl_down(p0, off, 64);
                    p1 += __shfl_down(p1, off, 64);
                }
                if (lane == 0) { s_fcp[wave][0] = p0; s_fcp[wave][1] = p1; }
                if (t < NT) {
                    dC = h1 - h1p; if (fabsf(dC) < THH) dC = 0.f; else h1p = h1;
                    nzC = dC != 0.f;
                }
            }
            mA = __ballot(nzA); mB = __ballot(nzB); mC = __ballot(nzC);
            if (lane == 0) {
                s_c1[wave] = __popcll(mA);
                s_c2[wave] = __popcll(mB);
                s_c3[wave] = __popcll(mC);
            }
        }
        __syncthreads();                                     // S3

        // ===== publish phase: entries via RELAXED LLC stores ==============
        if (tid < 128 && t < NT) {
            unsigned long long below = (1ull << lane) - 1;
            int preA = (wave == 1) ? s_c1[0] : 0;
            int preB = (wave == 1) ? s_c2[0] : 0;
            int preC = (wave == 1) ? s_c3[0] : 0;
            uint2* outA = lists + lofs(0, slot_w, bq, q);
            uint2* outB = lists + lofs(1, slot_w, bq, q);
            uint2* outC = lists + lofs(2, slot_w, bq, q);
            if (nzA) st_ent(&outA[preA + __popcll(mA & below)],
                            (unsigned)(uu * 6144u), __float_as_uint(dA));
            if (nzB) st_ent(&outB[preB + __popcll(mB & below)],
                            (unsigned)(uu * 6144u), __float_as_uint(dB));
            if (nzC) st_ent(&outC[preC + __popcll(mC & below)],
                            (unsigned)(uu * 6144u), __float_as_uint(dC));
        }
        if (t > 0 && tid == 0) {
            float2* dst = (float2*)(ws_fc + (((size_t)bq * NT + (t - 1)) * 4 + q) * 2);
            *dst = make_float2(s_fcp[0][0] + s_fcp[1][0],
                               s_fcp[0][1] + s_fcp[1][1]);
        }
        __syncthreads();     // S4: vmcnt(0) drain -> entry stores complete at LLC

        // ===== publish packed count word (RELAXED: ordering by S4 drain) ==
        if (t < NT && tid == 0) {
            unsigned word = ((unsigned)((t + 1) & 0xFF) << 24)
                          | ((unsigned)(s_c3[0] + s_c3[1]) << 16)
                          | ((unsigned)(s_c2[0] + s_c2[1]) << 8)
                          |  (unsigned)(s_c1[0] + s_c1[1]);
            st_cnt(&cnts[widx(slot_w, bq, q)], (int)word);
        }
    }
}

// ---- epilogue: deterministic FC reduction over 4 quarters (ascending) ----
__global__ void fc_reduce(const float* __restrict__ ws_fc,
                          const float* __restrict__ bfc,
                          float* __restrict__ out) {
    int idx = blockIdx.x * blockDim.x + threadIdx.x;   // (b*NT + t)
    if (idx < NB * NT) {
        const float2* p = (const float2*)(ws_fc + (size_t)idx * 8);
        out[idx * 2 + 0] = bfc[0] + p[0].x + p[1].x + p[2].x + p[3].x;
        out[idx * 2 + 1] = bfc[1] + p[0].y + p[1].y + p[2].y + p[3].y;
    }
}

// ---- safety-net fallback (ws too small): dense branchy loops, inline FC ----
__global__ __launch_bounds__(512)
void dgru_raw(const float* __restrict__ x,
              const float* __restrict__ wih0, const float* __restrict__ whh0,
              const float* __restrict__ wih1, const float* __restrict__ whh1,
              const float* __restrict__ bih0, const float* __restrict__ bhh0,
              const float* __restrict__ bih1, const float* __restrict__ bhh1,
              const float* __restrict__ wfc,  const float* __restrict__ bfc,
              float* __restrict__ out) {
    __shared__ float s_dx0[8];
    __shared__ float s_xp0[8];
    __shared__ float s_dh0[HID];
    __shared__ float s_dx1[HID];
    __shared__ float s_dh1[HID];
    __shared__ float s_part[16];

    const int j = threadIdx.x;
    const int b = blockIdx.x;
    float h0 = 0.f, h0p = 0.f, xp1 = 0.f, h1 = 0.f, h1p = 0.f;
    float cr0 = bih0[j] + bhh0[j];
    float cz0 = bih0[HID + j] + bhh0[HID + j];
    float cn0 = bih0[2*HID + j];
    float cnh0 = bhh0[2*HID + j];
    float cr1 = bih1[j] + bhh1[j];
    float cz1 = bih1[HID + j] + bhh1[HID + j];
    float cn1 = bih1[2*HID + j];
    float cnh1 = bhh1[2*HID + j];
    if (j < 8) { s_xp0[j] = 0.f; s_dx0[j] = 0.f; }
    const float wfc0 = wfc[j], wfc1 = wfc[HID + j];
    __syncthreads();

    for (int t = 0; t < NT; ++t) {
        float d = h0 - h0p;
        if (fabsf(d) < THH) d = 0.f; else h0p = h0;
        s_dh0[j] = d;
        if (j < 6) {
            float iv = x[(b * NT + t) * 2 + 0];
            float qv = x[(b * NT + t) * 2 + 1];
            float amp = sqrtf(iv * iv + qv * qv);
            float f;
            if      (j == 0) f = iv;
            else if (j == 1) f = qv;
            else if (j == 2) f = amp;
            else if (j == 3) f = amp * amp * amp;
            else if (j == 4) f = qv / amp;
            else             f = iv / amp;
            float dx = f - s_xp0[j];
            if (fabsf(dx) < THX) dx = 0.f; else s_xp0[j] = f;
            s_dx0[j] = dx;
        }
        __syncthreads();
        {
            float ar = cr0, az = cz0, an = cn0, anh = cnh0;
            #pragma unroll
            for (int f = 0; f < 6; ++f) {
                float dv = s_dx0[f];
                ar += dv * wih0[j * 6 + f];
                az += dv * wih0[(HID + j) * 6 + f];
                an += dv * wih0[(2*HID + j) * 6 + f];
            }
            for (int k = 0; k < HID; ++k) {
                float dv = s_dh0[k];
                if (dv != 0.f) {
                    ar  += dv * whh0[j * HID + k];
                    az  += dv * whh0[(HID + j) * HID + k];
                    anh += dv * whh0[(2*HID + j) * HID + k];
                }
            }
            cr0 = ar; cz0 = az; cn0 = an; cnh0 = anh;
            float r = 1.f / (1.f + expf(-ar));
            float z = 1.f / (1.f + expf(-az));
            float n = tanhf(an + r * anh);
            h0 = (1.f - z) * n + z * h0;
        }
        float dxv = h0 - xp1;
        if (fabsf(dxv) < THX) dxv = 0.f; else xp1 = h0;
        s_dx1[j] = dxv;
        float dhv = h1 - h1p;
        if (fabsf(dhv) < THH) dhv = 0.f; else h1p = h1;
        s_dh1[j] = dhv;
        __syncthreads();
        {
            float ar = cr1, az = cz1, an = cn1, anh = cnh1;
            for (int k = 0; k < HID; ++k) {
                float dv = s_dx1[k];
                if (dv != 0.f) {
                    ar += dv * wih1[j * HID + k];
                    az += dv * wih1[(HID + j) * HID + k];
                    an += dv * wih1[(2*HID + j) * HID + k];
                }
            }
            for (int k = 0; k < HID; ++k) {
                float dv = s_dh1[k];
                if (dv != 0.f) {
                    ar  += dv * whh1[j * HID + k];
                    az  += dv * whh1[(HID + j) * HID + k];
                    anh += dv * whh1[(2*HID + j) * HID + k];
                }
            }
            cr1 = ar; cz1 = az; cn1 = an; cnh1 = anh;
            float r = 1.f / (1.f + expf(-ar));
            float z = 1.f / (1.f + expf(-az));
            float n = tanhf(an + r * anh);
            h1 = (1.f - z) * n + z * h1;
        }
        float p0 = h1 * wfc0, p1 = h1 * wfc1;
        #pragma unroll
        for (int off = 32; off > 0; off >>= 1) {
            p0 += __shfl_down(p0, off, 64);
            p1 += __shfl_down(p1, off, 64);
        }
        if ((j & 63) == 0) { s_part[(j >> 6) * 2] = p0; s_part[(j >> 6) * 2 + 1] = p1; }
        __syncthreads();
        if (j == 0) {
            float o0 = bfc[0], o1 = bfc[1];
            #pragma unroll
            for (int w = 0; w < 8; ++w) { o0 += s_part[w * 2]; o1 += s_part[w * 2 + 1]; }
            out[(b * NT + t) * 2 + 0] = o0;
            out[(b * NT + t) * 2 + 1] = o1;
        }
    }
}

extern "C" void kernel_launch(void* const* d_in, const int* in_sizes, int n_in,
                              void* d_out, int out_size, void* d_ws, size_t ws_size,
                              hipStream_t stream) {
    const float* x    = (const float*)d_in[0];
    // d_in[1] = h_0 : reference zero-inits h, input unused
    const float* wih0 = (const float*)d_in[2];
    const float* whh0 = (const float*)d_in[3];
    const float* bih0 = (const float*)d_in[4];
    const float* bhh0 = (const float*)d_in[5];
    const float* wih1 = (const float*)d_in[6];
    const float* whh1 = (const float*)d_in[7];
    const float* bih1 = (const float*)d_in[8];
    const float* bhh1 = (const float*)d_in[9];
    const float* wfc  = (const float*)d_in[10];
    const float* bfc  = (const float*)d_in[11];
    float* out = (float*)d_out;

    const size_t MAT3    = (size_t)HID * 1536 * sizeof(float);     // 3 MiB each
    const size_t o_ih0   = 0;                                       // 36,864 B
    const size_t o_hh0   = 6 * 1536 * sizeof(float);
    const size_t o_ih1   = o_hh0 + MAT3;
    const size_t o_hh1   = o_ih1 + MAT3;
    const size_t o_lists = o_hh1 + MAT3;
    const size_t LISTS_B = (size_t)3 * 4 * NB * 4 * 128 * 8;        // 3 MiB (4-deep)
    const size_t o_cnts  = o_lists + LISTS_B;
    const size_t o_fc    = o_cnts + (size_t)4 * NB * 4 * sizeof(int);
    const size_t FCB     = (size_t)NB * NT * 4 * 2 * sizeof(float); // 2 MiB
    const size_t need    = o_fc + FCB;                              // ~14.2 MiB

    if (ws_size >= need) {
        float* wt_ih0 = (float*)((char*)d_ws + o_ih0);
        float* wt_hh0 = (float*)((char*)d_ws + o_hh0);
        float* wt_ih1 = (float*)((char*)d_ws + o_ih1);
        float* wt_hh1 = (float*)((char*)d_ws + o_hh1);
        uint2* g_lists = (uint2*)((char*)d_ws + o_lists);
        int*   g_cnts  = (int*)((char*)d_ws + o_cnts);
        float* g_fc    = (float*)((char*)d_ws + o_fc);

        pack_ih0<<<(6 * HID + 255) / 256, 256, 0, stream>>>(wih0, wt_ih0);
        pack_h3<<<(HID * HID + 255) / 256, 256, 0, stream>>>(whh0, wt_hh0);
        pack_h3<<<(HID * HID + 255) / 256, 256, 0, stream>>>(wih1, wt_ih1);
        pack_h3<<<(HID * HID + 255) / 256, 256, 0, stream>>>(whh1, wt_hh1);
        init_ws<<<1, 1024, 0, stream>>>(g_cnts);
        dgru_q<<<4 * NB, 1024, 0, stream>>>(x, wt_ih0, wt_hh0, wt_ih1, wt_hh1,
                                            bih0, bhh0, bih1, bhh1, wfc,
                                            g_lists, g_cnts, g_fc);
        fc_reduce<<<(NB * NT + 255) / 256, 256, 0, stream>>>(g_fc, bfc, out);
    } else {
        dgru_raw<<<NB, HID, 0, stream>>>(x, wih0, whh0, wih1, whh1,
                                         bih0, bhh0, bih1, bhh1, wfc, bfc, out);
    }
}